// Round 6
// baseline (427.560 us; speedup 1.0000x reference)
//
#include <hip/hip_runtime.h>
#include <hip/hip_bf16.h>

typedef __attribute__((ext_vector_type(8))) short short8;   // 8 x bf16 bits = 4 VGPRs
typedef __attribute__((ext_vector_type(4))) float f32x4;

#define NW 4            // waves per block (256 threads: fine occupancy granularity)
#define BPW 16          // batches per wave
#define BPB (NW * BPW)  // 64 batches per block

static __device__ __forceinline__ unsigned pk_bf16(float a, float b) {
    unsigned d;
    asm("v_cvt_pk_bf16_f32 %0, %1, %2" : "=v"(d) : "v"(a), "v"(b));
    return d;
}

// round-to-nearest-even bf16, returning the 16 bits
static __device__ __forceinline__ unsigned rne16(float x) {
    unsigned u = __float_as_uint(x);
    return (u + 0x7fffu + ((u >> 16) & 1u)) >> 16;
}
static __device__ __forceinline__ unsigned rne_bf16_pair(float x, float y) {
    return rne16(x) | (rne16(y) << 16);
}

static __device__ __forceinline__ short8 pack_frag(f32x4 a, f32x4 b) {
    union { unsigned u[4]; short8 s; } u;
    u.u[0] = pk_bf16(a.x, a.y);
    u.u[1] = pk_bf16(a.z, a.w);
    u.u[2] = pk_bf16(b.x, b.y);
    u.u[3] = pk_bf16(b.z, b.w);
    return u.s;
}

// Stage B-operand fragments of W^T (B[k][n] = W[n][k_off + k]) into LDS in
// fragment order: entry idx = (kt*nct + ct)*64 + lane; lane holds 8 bf16 with
// k = kt*32 + (lane>>4)*8 + j, n = ct*16 + (lane&15).
static __device__ __forceinline__ void stage_bfrags(const float* __restrict__ w,
                                                    int row_stride, int k_off, int nct,
                                                    short8* lds, int tid) {
    const int total = 4 * nct * 64;
    for (int idx = tid; idx < total; idx += NW * 64) {
        int lane = idx & 63;
        int ct = (idx >> 6) % nct;
        int kt = idx / (64 * nct);
        int n = ct * 16 + (lane & 15);
        int k = kt * 32 + (lane >> 4) * 8;
        const float* p = w + (size_t)n * row_stride + k_off + k;
        f32x4 a = *(const f32x4*)p;
        f32x4 b = *(const f32x4*)(p + 4);
        lds[idx] = pack_frag(a, b);
    }
}

// Same, but split each element into bf16 hi + bf16 residual (hi -> lds_hi, lo -> lds_lo).
static __device__ __forceinline__ void stage_bfrags_split(const float* __restrict__ w,
                                                          int row_stride, int nct,
                                                          short8* lds_hi, short8* lds_lo,
                                                          int tid) {
    const int total = 4 * nct * 64;
    for (int idx = tid; idx < total; idx += NW * 64) {
        int lane = idx & 63;
        int ct = (idx >> 6) % nct;
        int kt = idx / (64 * nct);
        int n = ct * 16 + (lane & 15);
        int k = kt * 32 + (lane >> 4) * 8;
        const float* p = w + (size_t)n * row_stride + k;
        f32x4 a = *(const f32x4*)p;
        f32x4 b = *(const f32x4*)(p + 4);
        float xs[8] = {a.x, a.y, a.z, a.w, b.x, b.y, b.z, b.w};
        union { unsigned u[4]; short8 s; } uh, ul;
#pragma unroll
        for (int q = 0; q < 4; ++q) {
            float x = xs[2 * q], y = xs[2 * q + 1];
            unsigned hx = rne16(x), hy = rne16(y);
            uh.u[q] = hx | (hy << 16);
            ul.u[q] = rne_bf16_pair(x - __uint_as_float(hx << 16),
                                    y - __uint_as_float(hy << 16));
        }
        lds_hi[idx] = uh.s;
        lds_lo[idx] = ul.s;
    }
}

// One l-step: pack A-frags from fp32 va, MFMA logits (ct-outer, 1 acc live),
// shuffle-transpose to per-batch logit, flash-softmax update of (m, s, o).
// Numerically identical to R5's loop body.
static __device__ __forceinline__ void step_l(int l, int sq, const f32x4* va,
                                              const short8* wlds,
                                              const unsigned (*hkp)[2],
                                              const float* w2v, int lane, int lo,
                                              float& m, float& s, float (*o)[8]) {
    short8 af[4];
#pragma unroll
    for (int kt = 0; kt < 4; ++kt)
        af[kt] = pack_frag(va[2 * kt], va[2 * kt + 1]);

    float p0 = 0.f, p1 = 0.f, p2 = 0.f, p3 = 0.f;
#pragma unroll
    for (int ct = 0; ct < 8; ++ct) {
        f32x4 acc;
        acc.x = __uint_as_float(hkp[ct][0] << 16);
        acc.y = __uint_as_float(hkp[ct][0] & 0xffff0000u);
        acc.z = __uint_as_float(hkp[ct][1] << 16);
        acc.w = __uint_as_float(hkp[ct][1] & 0xffff0000u);
#pragma unroll
        for (int kt = 0; kt < 4; ++kt)
            acc = __builtin_amdgcn_mfma_f32_16x16x32_bf16(
                af[kt], wlds[(kt * 8 + ct) * 64 + lane], acc, 0, 0, 0);
        p0 += fmaxf(acc.x, 0.f) * w2v[ct];
        p1 += fmaxf(acc.y, 0.f) * w2v[ct];
        p2 += fmaxf(acc.z, 0.f) * w2v[ct];
        p3 += fmaxf(acc.w, 0.f) * w2v[ct];
    }
#pragma unroll
    for (int mm = 1; mm <= 8; mm <<= 1) {  // reduce across 16-lane column groups
        p0 += __shfl_xor(p0, mm);
        p1 += __shfl_xor(p1, mm);
        p2 += __shfl_xor(p2, mm);
        p3 += __shfl_xor(p3, mm);
    }
    // transpose: this lane keeps the logit of its own batch-row `lo`
    int sl = (lo >> 2) * 16;
    float t0 = __shfl(p0, sl), t1 = __shfl(p1, sl);
    float t2 = __shfl(p2, sl), t3 = __shfl(p3, sl);
    int r = lo & 3;
    float w = (r == 0) ? t0 : (r == 1) ? t1 : (r == 2) ? t2 : t3;

    // flash update (masked l: no-op)
    bool valid = (l <= sq);
    float mn = valid ? fmaxf(m, w) : m;
    float c = __expf(m - mn);              // ==1 when max unchanged; ==0 on first l
    float e = valid ? __expf(w - mn) : 0.f;
    s = s * c + e;
    m = mn;
#pragma unroll
    for (int kt = 0; kt < 4; ++kt) {
        o[kt][0] = o[kt][0] * c + e * va[2 * kt].x;
        o[kt][1] = o[kt][1] * c + e * va[2 * kt].y;
        o[kt][2] = o[kt][2] * c + e * va[2 * kt].z;
        o[kt][3] = o[kt][3] * c + e * va[2 * kt].w;
        o[kt][4] = o[kt][4] * c + e * va[2 * kt + 1].x;
        o[kt][5] = o[kt][5] * c + e * va[2 * kt + 1].y;
        o[kt][6] = o[kt][6] * c + e * va[2 * kt + 1].z;
        o[kt][7] = o[kt][7] * c + e * va[2 * kt + 1].w;
    }
}

// NOTE: measured on gfx950 (R1: (512,4)->64 VGPR, R4: (512,3)->84 VGPR): the
// 2nd __launch_bounds__ arg acts as CUDA-style min BLOCKS per CU. With 4-wave
// blocks, (256,3) -> 12 waves/CU -> ~168-VGPR cap. (Under the alternative
// waves-per-EU reading it is also a ~170 cap, so the setting is safe either way.)
__global__ __launch_bounds__(NW * 64, 3)
void mask_attn_fused(const float* __restrict__ value, const float* __restrict__ key,
                     const int* __restrict__ seq_len, const float* __restrict__ w1,
                     const float* __restrict__ b1, const float* __restrict__ w2,
                     const float* __restrict__ fcw, const float* __restrict__ fcb,
                     float* __restrict__ out, int B) {
    __shared__ short8 wlds[2048];  // 32 KiB: Wk -> Wv -> (fcw_hi | fcw_lo), time-shared

    const int tid = threadIdx.x;
    const int lane = tid & 63;
    const int g = lane >> 4;   // 0..3
    const int lo = lane & 15;  // 0..15

    const long long b0w = (long long)blockIdx.x * BPB + (long long)(tid >> 6) * BPW;
    long long vb = b0w + lo; if (vb > (long long)B - 1) vb = (long long)B - 1;

    // ---------- prefetch: first value tile + key, issued before any staging ----------
    const float* ap = value + vb * (9 * 128) + g * 8;
    f32x4 vaA[8], vaB[8];
#pragma unroll
    for (int h = 0; h < 8; ++h)
        vaA[h] = *(const f32x4*)(ap + (h >> 1) * 32 + (h & 1) * 4);
    f32x4 kv[8];
    const float* kp = key + vb * 128 + g * 8;
#pragma unroll
    for (int h = 0; h < 8; ++h)
        kv[h] = *(const f32x4*)(kp + (h >> 1) * 32 + (h & 1) * 4);

    // ---------- phase 1: Wk fragments -> LDS ----------
    stage_bfrags(w1, 2 * 128, 0, 8, wlds, tid);
    __syncthreads();

    // ---------- phase 2: HK = b1 + key @ Wk^T (ct-outer, 1 acc chain live) ----------
    // C/D layout: row = (lane>>4)*4 + reg (= batch index), col = ct*16 + (lane&15)
    unsigned hkp[8][2];
    {
        short8 af[4];
#pragma unroll
        for (int kt = 0; kt < 4; ++kt)
            af[kt] = pack_frag(kv[2 * kt], kv[2 * kt + 1]);
#pragma unroll
        for (int ct = 0; ct < 8; ++ct) {
            float bv = b1[ct * 16 + lo];
            f32x4 hk = (f32x4){bv, bv, bv, bv};
#pragma unroll
            for (int kt = 0; kt < 4; ++kt)
                hk = __builtin_amdgcn_mfma_f32_16x16x32_bf16(
                    af[kt], wlds[(kt * 8 + ct) * 64 + lane], hk, 0, 0, 0);
            hkp[ct][0] = rne_bf16_pair(hk.x, hk.y);
            hkp[ct][1] = rne_bf16_pair(hk.z, hk.w);
        }
    }
    __syncthreads();

    // ---------- phase 3: Wv fragments -> LDS ----------
    stage_bfrags(w1, 2 * 128, 128, 8, wlds, tid);
    __syncthreads();

    float w2v[8];
#pragma unroll
    for (int ct = 0; ct < 8; ++ct) w2v[ct] = w2[ct * 16 + lo];
    const int sq = seq_len[vb];  // valid positions: l <= sq (this lane's batch = lo row)

    // ---------- phase 4: software-pipelined fused l-loop ----------
    // Two named buffers (vaA/vaB; no runtime indexing -> stays in VGPRs). Loads for
    // l+1 are issued BEFORE the compute of l, so HBM latency hides under the
    // MFMA/shuffle/flash chain. Numerics identical to the non-pipelined version.
    float o[4][8];
#pragma unroll
    for (int kt = 0; kt < 4; ++kt)
#pragma unroll
        for (int j = 0; j < 8; ++j) o[kt][j] = 0.f;
    float s = 0.f, m = -3e38f;

#pragma unroll 1
    for (int l = 0; l < 9; l += 2) {
        if (l + 1 < 9) {
#pragma unroll
            for (int h = 0; h < 8; ++h)
                vaB[h] = *(const f32x4*)(ap + (l + 1) * 128 + (h >> 1) * 32 + (h & 1) * 4);
        }
        step_l(l, sq, vaA, wlds, hkp, w2v, lane, lo, m, s, o);
        if (l + 2 < 9) {
#pragma unroll
            for (int h = 0; h < 8; ++h)
                vaA[h] = *(const f32x4*)(ap + (l + 2) * 128 + (h >> 1) * 32 + (h & 1) * 4);
        }
        if (l + 1 < 9)
            step_l(l + 1, sq, vaB, wlds, hkp, w2v, lane, lo, m, s, o);
    }

    // normalize; split O into bf16 hi+lo fc A-fragments (row = lo, k = kt*32+g*8+j)
    const float rs = 1.f / s;  // s>0 always: l=0 is always valid (sq >= 0)
    short8 afoh[4], afol[4];
#pragma unroll
    for (int kt = 0; kt < 4; ++kt) {
        union { unsigned u[4]; short8 v; } uh, ul;
#pragma unroll
        for (int p = 0; p < 4; ++p) {
            float x = o[kt][2 * p] * rs, y = o[kt][2 * p + 1] * rs;
            unsigned hx = rne16(x), hy = rne16(y);
            uh.u[p] = hx | (hy << 16);
            ul.u[p] = rne_bf16_pair(x - __uint_as_float(hx << 16),
                                    y - __uint_as_float(hy << 16));
        }
        afoh[kt] = uh.v;
        afol[kt] = ul.v;
    }

    __syncthreads();
    // ---------- phase 5: fcw hi/lo fragments -> LDS (hi: [0,1024), lo: [1024,2048)) --
    stage_bfrags_split(fcw, 128, 4, wlds, wlds + 1024, tid);
    __syncthreads();

    // ---------- phase 6: out = relu(O @ fcw^T + fcb), split-bf16 (3 cross terms) ----
    {
        f32x4 facc[4];
#pragma unroll
        for (int ct = 0; ct < 4; ++ct) {
            float fb = fcb[ct * 16 + lo];
            facc[ct] = (f32x4){fb, fb, fb, fb};
        }
#pragma unroll
        for (int kt = 0; kt < 4; ++kt)
#pragma unroll
            for (int ct = 0; ct < 4; ++ct) {
                short8 wh = wlds[(kt * 4 + ct) * 64 + lane];
                short8 wl = wlds[1024 + (kt * 4 + ct) * 64 + lane];
                facc[ct] = __builtin_amdgcn_mfma_f32_16x16x32_bf16(afoh[kt], wh, facc[ct], 0, 0, 0);
                facc[ct] = __builtin_amdgcn_mfma_f32_16x16x32_bf16(afol[kt], wh, facc[ct], 0, 0, 0);
                facc[ct] = __builtin_amdgcn_mfma_f32_16x16x32_bf16(afoh[kt], wl, facc[ct], 0, 0, 0);
            }
#pragma unroll
        for (int ct = 0; ct < 4; ++ct) {
            float v0 = fmaxf(facc[ct].x, 0.f), v1 = fmaxf(facc[ct].y, 0.f);
            float v2 = fmaxf(facc[ct].z, 0.f), v3 = fmaxf(facc[ct].w, 0.f);
            long long bo = b0w + g * 4;
            if (bo + 0 < B) out[(bo + 0) * 64 + ct * 16 + lo] = v0;
            if (bo + 1 < B) out[(bo + 1) * 64 + ct * 16 + lo] = v1;
            if (bo + 2 < B) out[(bo + 2) * 64 + ct * 16 + lo] = v2;
            if (bo + 3 < B) out[(bo + 3) * 64 + ct * 16 + lo] = v3;
        }
    }
}

extern "C" void kernel_launch(void* const* d_in, const int* in_sizes, int n_in,
                              void* d_out, int out_size, void* d_ws, size_t ws_size,
                              hipStream_t stream) {
    const float* value = (const float*)d_in[0];
    const float* key   = (const float*)d_in[1];
    const int*   seq   = (const int*)d_in[2];
    // d_in[3] = maxlen (unused; L == 9 fixed by reference)
    const float* w1    = (const float*)d_in[4];
    const float* b1    = (const float*)d_in[5];
    const float* w2    = (const float*)d_in[6];
    // d_in[7] = b2: softmax-invariant, dropped
    const float* fcw   = (const float*)d_in[8];
    const float* fcb   = (const float*)d_in[9];
    float* out = (float*)d_out;

    int B = in_sizes[1] / 128;
    int blocks = (B + BPB - 1) / BPB;
    mask_attn_fused<<<blocks, NW * 64, 0, stream>>>(value, key, seq, w1, b1, w2, fcw, fcb, out, B);
}

// Round 7
// 143.818 us; speedup vs baseline: 2.9729x; 2.9729x over previous
//
#include <hip/hip_runtime.h>
#include <hip/hip_bf16.h>

typedef __attribute__((ext_vector_type(8))) short short8;   // 8 x bf16 bits = 4 VGPRs
typedef __attribute__((ext_vector_type(4))) float f32x4;

#define NW 4            // waves per block (256 threads)
#define BPW 16          // batches per wave
#define BPB (NW * BPW)  // 64 batches per block

static __device__ __forceinline__ unsigned pk_bf16(float a, float b) {
    unsigned d;
    asm("v_cvt_pk_bf16_f32 %0, %1, %2" : "=v"(d) : "v"(a), "v"(b));
    return d;
}

// round-to-nearest-even bf16, returning the 16 bits
static __device__ __forceinline__ unsigned rne16(float x) {
    unsigned u = __float_as_uint(x);
    return (u + 0x7fffu + ((u >> 16) & 1u)) >> 16;
}
static __device__ __forceinline__ unsigned rne_bf16_pair(float x, float y) {
    return rne16(x) | (rne16(y) << 16);
}

static __device__ __forceinline__ short8 pack_frag(f32x4 a, f32x4 b) {
    union { unsigned u[4]; short8 s; } u;
    u.u[0] = pk_bf16(a.x, a.y);
    u.u[1] = pk_bf16(a.z, a.w);
    u.u[2] = pk_bf16(b.x, b.y);
    u.u[3] = pk_bf16(b.z, b.w);
    return u.s;
}

// Stage B-operand fragments of W^T (B[k][n] = W[n][k_off + k]) into LDS in
// fragment order: entry idx = (kt*nct + ct)*64 + lane; lane holds 8 bf16 with
// k = kt*32 + (lane>>4)*8 + j, n = ct*16 + (lane&15).
static __device__ __forceinline__ void stage_bfrags(const float* __restrict__ w,
                                                    int row_stride, int k_off, int nct,
                                                    short8* lds, int tid) {
    const int total = 4 * nct * 64;
    for (int idx = tid; idx < total; idx += NW * 64) {
        int lane = idx & 63;
        int ct = (idx >> 6) % nct;
        int kt = idx / (64 * nct);
        int n = ct * 16 + (lane & 15);
        int k = kt * 32 + (lane >> 4) * 8;
        const float* p = w + (size_t)n * row_stride + k_off + k;
        f32x4 a = *(const f32x4*)p;
        f32x4 b = *(const f32x4*)(p + 4);
        lds[idx] = pack_frag(a, b);
    }
}

// Same, but split each element into bf16 hi + bf16 residual (hi -> lds_hi, lo -> lds_lo).
static __device__ __forceinline__ void stage_bfrags_split(const float* __restrict__ w,
                                                          int row_stride, int nct,
                                                          short8* lds_hi, short8* lds_lo,
                                                          int tid) {
    const int total = 4 * nct * 64;
    for (int idx = tid; idx < total; idx += NW * 64) {
        int lane = idx & 63;
        int ct = (idx >> 6) % nct;
        int kt = idx / (64 * nct);
        int n = ct * 16 + (lane & 15);
        int k = kt * 32 + (lane >> 4) * 8;
        const float* p = w + (size_t)n * row_stride + k;
        f32x4 a = *(const f32x4*)p;
        f32x4 b = *(const f32x4*)(p + 4);
        float xs[8] = {a.x, a.y, a.z, a.w, b.x, b.y, b.z, b.w};
        union { unsigned u[4]; short8 s; } uh, ul;
#pragma unroll
        for (int q = 0; q < 4; ++q) {
            float x = xs[2 * q], y = xs[2 * q + 1];
            unsigned hx = rne16(x), hy = rne16(y);
            uh.u[q] = hx | (hy << 16);
            ul.u[q] = rne_bf16_pair(x - __uint_as_float(hx << 16),
                                    y - __uint_as_float(hy << 16));
        }
        lds_hi[idx] = uh.s;
        lds_lo[idx] = ul.s;
    }
}

// One l-step: pack A-frags from fp32 va, MFMA logits (ct-outer, 1 acc live),
// shuffle-transpose to per-batch logit, flash-softmax update of (m, s, o).
// Numerically identical to R5's loop body.
static __device__ __forceinline__ void step_l(int l, int sq, const f32x4* va,
                                              const short8* wlds,
                                              const unsigned (*hkp)[2],
                                              const float* w2v, int lane, int lo,
                                              float& m, float& s, float (*o)[8]) {
    short8 af[4];
#pragma unroll
    for (int kt = 0; kt < 4; ++kt)
        af[kt] = pack_frag(va[2 * kt], va[2 * kt + 1]);

    float p0 = 0.f, p1 = 0.f, p2 = 0.f, p3 = 0.f;
#pragma unroll
    for (int ct = 0; ct < 8; ++ct) {
        f32x4 acc;
        acc.x = __uint_as_float(hkp[ct][0] << 16);
        acc.y = __uint_as_float(hkp[ct][0] & 0xffff0000u);
        acc.z = __uint_as_float(hkp[ct][1] << 16);
        acc.w = __uint_as_float(hkp[ct][1] & 0xffff0000u);
#pragma unroll
        for (int kt = 0; kt < 4; ++kt)
            acc = __builtin_amdgcn_mfma_f32_16x16x32_bf16(
                af[kt], wlds[(kt * 8 + ct) * 64 + lane], acc, 0, 0, 0);
        p0 += fmaxf(acc.x, 0.f) * w2v[ct];
        p1 += fmaxf(acc.y, 0.f) * w2v[ct];
        p2 += fmaxf(acc.z, 0.f) * w2v[ct];
        p3 += fmaxf(acc.w, 0.f) * w2v[ct];
    }
#pragma unroll
    for (int mm = 1; mm <= 8; mm <<= 1) {  // reduce across 16-lane column groups
        p0 += __shfl_xor(p0, mm);
        p1 += __shfl_xor(p1, mm);
        p2 += __shfl_xor(p2, mm);
        p3 += __shfl_xor(p3, mm);
    }
    // transpose: this lane keeps the logit of its own batch-row `lo`
    int sl = (lo >> 2) * 16;
    float t0 = __shfl(p0, sl), t1 = __shfl(p1, sl);
    float t2 = __shfl(p2, sl), t3 = __shfl(p3, sl);
    int r = lo & 3;
    float w = (r == 0) ? t0 : (r == 1) ? t1 : (r == 2) ? t2 : t3;

    // flash update (masked l: no-op)
    bool valid = (l <= sq);
    float mn = valid ? fmaxf(m, w) : m;
    float c = __expf(m - mn);              // ==1 when max unchanged; ==0 on first l
    float e = valid ? __expf(w - mn) : 0.f;
    s = s * c + e;
    m = mn;
#pragma unroll
    for (int kt = 0; kt < 4; ++kt) {
        o[kt][0] = o[kt][0] * c + e * va[2 * kt].x;
        o[kt][1] = o[kt][1] * c + e * va[2 * kt].y;
        o[kt][2] = o[kt][2] * c + e * va[2 * kt].z;
        o[kt][3] = o[kt][3] * c + e * va[2 * kt].w;
        o[kt][4] = o[kt][4] * c + e * va[2 * kt + 1].x;
        o[kt][5] = o[kt][5] * c + e * va[2 * kt + 1].y;
        o[kt][6] = o[kt][6] * c + e * va[2 * kt + 1].z;
        o[kt][7] = o[kt][7] * c + e * va[2 * kt + 1].w;
    }
}

// MEASURED launch-bounds rule on gfx950 hipcc (R1/R4/R6): VGPR cap = 256 / arg,
// INDEPENDENT of block size ((512,4)->64, (512,3)->84, (256,3)->84). It is
// neither CUDA min-blocks nor waves-per-EU. arg=1 -> 256 cap: lets the 2-deep
// pipeline (~160-190 live) allocate without spilling; HW occupancy then follows
// actual VGPR use (~3 waves/SIMD).
__global__ __launch_bounds__(NW * 64, 1)
void mask_attn_fused(const float* __restrict__ value, const float* __restrict__ key,
                     const int* __restrict__ seq_len, const float* __restrict__ w1,
                     const float* __restrict__ b1, const float* __restrict__ w2,
                     const float* __restrict__ fcw, const float* __restrict__ fcb,
                     float* __restrict__ out, int B) {
    __shared__ short8 wlds[2048];  // 32 KiB: Wk -> Wv -> (fcw_hi | fcw_lo), time-shared

    const int tid = threadIdx.x;
    const int lane = tid & 63;
    const int g = lane >> 4;   // 0..3
    const int lo = lane & 15;  // 0..15

    const long long b0w = (long long)blockIdx.x * BPB + (long long)(tid >> 6) * BPW;
    long long vb = b0w + lo; if (vb > (long long)B - 1) vb = (long long)B - 1;

    // ---------- prefetch: first value tile + key, issued before any staging ----------
    const float* ap = value + vb * (9 * 128) + g * 8;
    f32x4 vaA[8], vaB[8];
#pragma unroll
    for (int h = 0; h < 8; ++h)
        vaA[h] = *(const f32x4*)(ap + (h >> 1) * 32 + (h & 1) * 4);
    f32x4 kv[8];
    const float* kp = key + vb * 128 + g * 8;
#pragma unroll
    for (int h = 0; h < 8; ++h)
        kv[h] = *(const f32x4*)(kp + (h >> 1) * 32 + (h & 1) * 4);

    // ---------- phase 1: Wk fragments -> LDS ----------
    stage_bfrags(w1, 2 * 128, 0, 8, wlds, tid);
    __syncthreads();

    // ---------- phase 2: HK = b1 + key @ Wk^T (ct-outer, 1 acc chain live) ----------
    // C/D layout: row = (lane>>4)*4 + reg (= batch index), col = ct*16 + (lane&15)
    unsigned hkp[8][2];
    {
        short8 af[4];
#pragma unroll
        for (int kt = 0; kt < 4; ++kt)
            af[kt] = pack_frag(kv[2 * kt], kv[2 * kt + 1]);
#pragma unroll
        for (int ct = 0; ct < 8; ++ct) {
            float bv = b1[ct * 16 + lo];
            f32x4 hk = (f32x4){bv, bv, bv, bv};
#pragma unroll
            for (int kt = 0; kt < 4; ++kt)
                hk = __builtin_amdgcn_mfma_f32_16x16x32_bf16(
                    af[kt], wlds[(kt * 8 + ct) * 64 + lane], hk, 0, 0, 0);
            hkp[ct][0] = rne_bf16_pair(hk.x, hk.y);
            hkp[ct][1] = rne_bf16_pair(hk.z, hk.w);
        }
    }
    __syncthreads();

    // ---------- phase 3: Wv fragments -> LDS ----------
    stage_bfrags(w1, 2 * 128, 128, 8, wlds, tid);
    __syncthreads();

    float w2v[8];
#pragma unroll
    for (int ct = 0; ct < 8; ++ct) w2v[ct] = w2[ct * 16 + lo];
    const int sq = seq_len[vb];  // valid positions: l <= sq (this lane's batch = lo row)

    // ---------- phase 4: software-pipelined fused l-loop ----------
    // Two named buffers (vaA/vaB; no runtime indexing -> stays in VGPRs). Loads for
    // l+1 are issued BEFORE the compute of l, so HBM latency hides under the
    // MFMA/shuffle/flash chain. Numerics identical to the non-pipelined version.
    float o[4][8];
#pragma unroll
    for (int kt = 0; kt < 4; ++kt)
#pragma unroll
        for (int j = 0; j < 8; ++j) o[kt][j] = 0.f;
    float s = 0.f, m = -3e38f;

#pragma unroll 1
    for (int l = 0; l < 9; l += 2) {
        if (l + 1 < 9) {
#pragma unroll
            for (int h = 0; h < 8; ++h)
                vaB[h] = *(const f32x4*)(ap + (l + 1) * 128 + (h >> 1) * 32 + (h & 1) * 4);
        }
        step_l(l, sq, vaA, wlds, hkp, w2v, lane, lo, m, s, o);
        if (l + 2 < 9) {
#pragma unroll
            for (int h = 0; h < 8; ++h)
                vaA[h] = *(const f32x4*)(ap + (l + 2) * 128 + (h >> 1) * 32 + (h & 1) * 4);
        }
        if (l + 1 < 9)
            step_l(l + 1, sq, vaB, wlds, hkp, w2v, lane, lo, m, s, o);
    }

    // normalize; split O into bf16 hi+lo fc A-fragments (row = lo, k = kt*32+g*8+j)
    const float rs = 1.f / s;  // s>0 always: l=0 is always valid (sq >= 0)
    short8 afoh[4], afol[4];
#pragma unroll
    for (int kt = 0; kt < 4; ++kt) {
        union { unsigned u[4]; short8 v; } uh, ul;
#pragma unroll
        for (int p = 0; p < 4; ++p) {
            float x = o[kt][2 * p] * rs, y = o[kt][2 * p + 1] * rs;
            unsigned hx = rne16(x), hy = rne16(y);
            uh.u[p] = hx | (hy << 16);
            ul.u[p] = rne_bf16_pair(x - __uint_as_float(hx << 16),
                                    y - __uint_as_float(hy << 16));
        }
        afoh[kt] = uh.v;
        afol[kt] = ul.v;
    }

    __syncthreads();
    // ---------- phase 5: fcw hi/lo fragments -> LDS (hi: [0,1024), lo: [1024,2048)) --
    stage_bfrags_split(fcw, 128, 4, wlds, wlds + 1024, tid);
    __syncthreads();

    // ---------- phase 6: out = relu(O @ fcw^T + fcb), split-bf16 (3 cross terms) ----
    {
        f32x4 facc[4];
#pragma unroll
        for (int ct = 0; ct < 4; ++ct) {
            float fb = fcb[ct * 16 + lo];
            facc[ct] = (f32x4){fb, fb, fb, fb};
        }
#pragma unroll
        for (int kt = 0; kt < 4; ++kt)
#pragma unroll
            for (int ct = 0; ct < 4; ++ct) {
                short8 wh = wlds[(kt * 4 + ct) * 64 + lane];
                short8 wl = wlds[1024 + (kt * 4 + ct) * 64 + lane];
                facc[ct] = __builtin_amdgcn_mfma_f32_16x16x32_bf16(afoh[kt], wh, facc[ct], 0, 0, 0);
                facc[ct] = __builtin_amdgcn_mfma_f32_16x16x32_bf16(afol[kt], wh, facc[ct], 0, 0, 0);
                facc[ct] = __builtin_amdgcn_mfma_f32_16x16x32_bf16(afoh[kt], wl, facc[ct], 0, 0, 0);
            }
#pragma unroll
        for (int ct = 0; ct < 4; ++ct) {
            float v0 = fmaxf(facc[ct].x, 0.f), v1 = fmaxf(facc[ct].y, 0.f);
            float v2 = fmaxf(facc[ct].z, 0.f), v3 = fmaxf(facc[ct].w, 0.f);
            long long bo = b0w + g * 4;
            if (bo + 0 < B) out[(bo + 0) * 64 + ct * 16 + lo] = v0;
            if (bo + 1 < B) out[(bo + 1) * 64 + ct * 16 + lo] = v1;
            if (bo + 2 < B) out[(bo + 2) * 64 + ct * 16 + lo] = v2;
            if (bo + 3 < B) out[(bo + 3) * 64 + ct * 16 + lo] = v3;
        }
    }
}

extern "C" void kernel_launch(void* const* d_in, const int* in_sizes, int n_in,
                              void* d_out, int out_size, void* d_ws, size_t ws_size,
                              hipStream_t stream) {
    const float* value = (const float*)d_in[0];
    const float* key   = (const float*)d_in[1];
    const int*   seq   = (const int*)d_in[2];
    // d_in[3] = maxlen (unused; L == 9 fixed by reference)
    const float* w1    = (const float*)d_in[4];
    const float* b1    = (const float*)d_in[5];
    const float* w2    = (const float*)d_in[6];
    // d_in[7] = b2: softmax-invariant, dropped
    const float* fcw   = (const float*)d_in[8];
    const float* fcb   = (const float*)d_in[9];
    float* out = (float*)d_out;

    int B = in_sizes[1] / 128;
    int blocks = (B + BPB - 1) / BPB;
    mask_attn_fused<<<blocks, NW * 64, 0, stream>>>(value, key, seq, w1, b1, w2, fcw, fcb, out, B);
}

// Round 8
// 90.042 us; speedup vs baseline: 4.7484x; 1.5972x over previous
//
#include <hip/hip_runtime.h>
#include <hip/hip_bf16.h>

typedef __attribute__((ext_vector_type(8))) short short8;   // 8 x bf16 bits = 4 VGPRs
typedef __attribute__((ext_vector_type(4))) float f32x4;

#define NW 8            // waves per block (512 threads)
#define BPW 16          // batches per wave
#define BPB (NW * BPW)  // 128 batches per block

static __device__ __forceinline__ unsigned pk_bf16(float a, float b) {
    unsigned d;
    asm("v_cvt_pk_bf16_f32 %0, %1, %2" : "=v"(d) : "v"(a), "v"(b));
    return d;
}

// round-to-nearest-even bf16, returning the 16 bits
static __device__ __forceinline__ unsigned rne16(float x) {
    unsigned u = __float_as_uint(x);
    return (u + 0x7fffu + ((u >> 16) & 1u)) >> 16;
}
static __device__ __forceinline__ unsigned rne_bf16_pair(float x, float y) {
    return rne16(x) | (rne16(y) << 16);
}

static __device__ __forceinline__ short8 pack_frag(f32x4 a, f32x4 b) {
    union { unsigned u[4]; short8 s; } u;
    u.u[0] = pk_bf16(a.x, a.y);
    u.u[1] = pk_bf16(a.z, a.w);
    u.u[2] = pk_bf16(b.x, b.y);
    u.u[3] = pk_bf16(b.z, b.w);
    return u.s;
}

// Stage B-operand fragments of W^T (B[k][n] = W[n][k_off + k]) into LDS in
// fragment order: entry idx = (kt*nct + ct)*64 + lane; lane holds 8 bf16 with
// k = kt*32 + (lane>>4)*8 + j, n = ct*16 + (lane&15).
static __device__ __forceinline__ void stage_bfrags(const float* __restrict__ w,
                                                    int row_stride, int k_off, int nct,
                                                    short8* lds, int tid) {
    const int total = 4 * nct * 64;
    for (int idx = tid; idx < total; idx += NW * 64) {
        int lane = idx & 63;
        int ct = (idx >> 6) % nct;
        int kt = idx / (64 * nct);
        int n = ct * 16 + (lane & 15);
        int k = kt * 32 + (lane >> 4) * 8;
        const float* p = w + (size_t)n * row_stride + k_off + k;
        f32x4 a = *(const f32x4*)p;
        f32x4 b = *(const f32x4*)(p + 4);
        lds[idx] = pack_frag(a, b);
    }
}

// Same, but split each element into bf16 hi + bf16 residual (hi -> lds_hi, lo -> lds_lo).
static __device__ __forceinline__ void stage_bfrags_split(const float* __restrict__ w,
                                                          int row_stride, int nct,
                                                          short8* lds_hi, short8* lds_lo,
                                                          int tid) {
    const int total = 4 * nct * 64;
    for (int idx = tid; idx < total; idx += NW * 64) {
        int lane = idx & 63;
        int ct = (idx >> 6) % nct;
        int kt = idx / (64 * nct);
        int n = ct * 16 + (lane & 15);
        int k = kt * 32 + (lane >> 4) * 8;
        const float* p = w + (size_t)n * row_stride + k;
        f32x4 a = *(const f32x4*)p;
        f32x4 b = *(const f32x4*)(p + 4);
        float xs[8] = {a.x, a.y, a.z, a.w, b.x, b.y, b.z, b.w};
        union { unsigned u[4]; short8 s; } uh, ul;
#pragma unroll
        for (int q = 0; q < 4; ++q) {
            float x = xs[2 * q], y = xs[2 * q + 1];
            unsigned hx = rne16(x), hy = rne16(y);
            uh.u[q] = hx | (hy << 16);
            ul.u[q] = rne_bf16_pair(x - __uint_as_float(hx << 16),
                                    y - __uint_as_float(hy << 16));
        }
        lds_hi[idx] = uh.s;
        lds_lo[idx] = ul.s;
    }
}

// MEASURED launch-bounds rule on gfx950 hipcc (3 points: (512,4)->64,
// (512,3)->84, (256,3)->84): VGPR cap = 256 / arg, independent of block size.
// (512,2) -> hard 128 cap. Kernel is register-engineered (value as bf16 hi+lo,
// hk & w2 in LDS) so the 2-deep pipelined live set is ~124 <= 128: full
// prefetch AND 4 waves/SIMD (16 waves/CU; LDS 65KB -> 2 blocks/CU).
__global__ __launch_bounds__(NW * 64, 2)
void mask_attn_fused(const float* __restrict__ value, const float* __restrict__ key,
                     const int* __restrict__ seq_len, const float* __restrict__ w1,
                     const float* __restrict__ b1, const float* __restrict__ w2,
                     const float* __restrict__ fcw, const float* __restrict__ fcb,
                     float* __restrict__ out, int B) {
    __shared__ short8 wlds[2048];            // 32 KiB: Wk -> Wv -> (fcw_hi|fcw_lo)
    __shared__ uint2 hklds[NW * 8 * 64];     // 32 KiB: per-wave hk init (bf16-pair bits)
    __shared__ float w2lds[128];             // 512 B

    const int tid = threadIdx.x;
    const int wave = tid >> 6;
    const int lane = tid & 63;
    const int g = lane >> 4;   // 0..3
    const int lo = lane & 15;  // 0..15

    const long long b0w = (long long)blockIdx.x * BPB + (long long)wave * BPW;
    long long vb = b0w + lo; if (vb > (long long)B - 1) vb = (long long)B - 1;

    // ---------- prologue: issue tile-0 value loads + key loads FIRST ----------
    const float* ap = value + vb * (9 * 128) + g * 8;
    f32x4 raw[8];
#pragma unroll
    for (int h = 0; h < 8; ++h)
        raw[h] = *(const f32x4*)(ap + (h >> 1) * 32 + (h & 1) * 4);
    f32x4 kv[8];
    const float* kp = key + vb * 128 + g * 8;
#pragma unroll
    for (int h = 0; h < 8; ++h)
        kv[h] = *(const f32x4*)(kp + (h >> 1) * 32 + (h & 1) * 4);

    if (tid < 128) w2lds[tid] = w2[tid];

    // ---------- phase 1: Wk fragments -> LDS ----------
    stage_bfrags(w1, 2 * 128, 0, 8, wlds, tid);
    __syncthreads();

    // ---------- phase 2: HK = b1 + key @ Wk^T; store bf16-pair bits to LDS ----------
    // C/D layout: row = (lane>>4)*4 + reg (= batch index), col = ct*16 + (lane&15)
    {
        short8 af[4];
#pragma unroll
        for (int kt = 0; kt < 4; ++kt)
            af[kt] = pack_frag(kv[2 * kt], kv[2 * kt + 1]);
#pragma unroll
        for (int ct = 0; ct < 8; ++ct) {
            float bv = b1[ct * 16 + lo];
            f32x4 hk = (f32x4){bv, bv, bv, bv};
#pragma unroll
            for (int kt = 0; kt < 4; ++kt)
                hk = __builtin_amdgcn_mfma_f32_16x16x32_bf16(
                    af[kt], wlds[(kt * 8 + ct) * 64 + lane], hk, 0, 0, 0);
            uint2 pk;
            pk.x = rne_bf16_pair(hk.x, hk.y);
            pk.y = rne_bf16_pair(hk.z, hk.w);
            hklds[wave * 512 + ct * 64 + lane] = pk;
        }
    }
    __syncthreads();

    // ---------- phase 3: Wv fragments -> LDS ----------
    stage_bfrags(w1, 2 * 128, 128, 8, wlds, tid);
    __syncthreads();

    const int sq = seq_len[vb];  // valid positions: l <= sq (this lane's batch = lo row)
    const uint2* hkw = hklds + wave * 512;

    // ---------- phase 4: pipelined fused l-loop ----------
    // Step l: convert raw(fp32, arrived) -> af(bf16 hi) + alo(bf16 residual); raw
    // dies; immediately issue tile l+1 loads into raw (in flight under the whole
    // MFMA/shuffle/flash chain). o-update uses hi+lo (exact in fp32 to 2^-17 rel).
    float o[4][8];
#pragma unroll
    for (int kt = 0; kt < 4; ++kt)
#pragma unroll
        for (int j = 0; j < 8; ++j) o[kt][j] = 0.f;
    float s = 0.f, m = -3e38f;

#pragma unroll 1
    for (int l = 0; l < 9; ++l) {
        // convert: raw -> af + alo (then raw is reusable)
        short8 af[4], alo[4];
#pragma unroll
        for (int kt = 0; kt < 4; ++kt) {
            f32x4 a = raw[2 * kt], b = raw[2 * kt + 1];
            af[kt] = pack_frag(a, b);
            float xs[8] = {a.x, a.y, a.z, a.w, b.x, b.y, b.z, b.w};
            union { unsigned u[4]; short8 s; } ul;
#pragma unroll
            for (int q = 0; q < 4; ++q) {
                float x = xs[2 * q], y = xs[2 * q + 1];
                float hxf = __uint_as_float(__float_as_uint(x) & 0xffff0000u);
                float hyf = __uint_as_float(__float_as_uint(y) & 0xffff0000u);
                // NB: af holds RNE-rounded hi; residual vs TRUNC-hi here would be
                // inconsistent. Use RNE-hi for the residual base:
                unsigned hx = rne16(x), hy = rne16(y);
                (void)hxf; (void)hyf;
                ul.u[q] = pk_bf16(x - __uint_as_float(hx << 16),
                                  y - __uint_as_float(hy << 16));
            }
            alo[kt] = ul.s;
        }
        // issue next tile's loads into raw
        if (l + 1 < 9) {
#pragma unroll
            for (int h = 0; h < 8; ++h)
                raw[h] = *(const f32x4*)(ap + (l + 1) * 128 + (h >> 1) * 32 + (h & 1) * 4);
        }

        // logit partials: one acc chain per ct; hk init from LDS; w2 from LDS
        float p0 = 0.f, p1 = 0.f, p2 = 0.f, p3 = 0.f;
#pragma unroll
        for (int ct = 0; ct < 8; ++ct) {
            uint2 hkv = hkw[ct * 64 + lane];
            f32x4 acc;
            acc.x = __uint_as_float(hkv.x << 16);
            acc.y = __uint_as_float(hkv.x & 0xffff0000u);
            acc.z = __uint_as_float(hkv.y << 16);
            acc.w = __uint_as_float(hkv.y & 0xffff0000u);
#pragma unroll
            for (int kt = 0; kt < 4; ++kt)
                acc = __builtin_amdgcn_mfma_f32_16x16x32_bf16(
                    af[kt], wlds[(kt * 8 + ct) * 64 + lane], acc, 0, 0, 0);
            float wv = w2lds[ct * 16 + lo];
            p0 += fmaxf(acc.x, 0.f) * wv;
            p1 += fmaxf(acc.y, 0.f) * wv;
            p2 += fmaxf(acc.z, 0.f) * wv;
            p3 += fmaxf(acc.w, 0.f) * wv;
        }
#pragma unroll
        for (int mm = 1; mm <= 8; mm <<= 1) {  // reduce across 16-lane column groups
            p0 += __shfl_xor(p0, mm);
            p1 += __shfl_xor(p1, mm);
            p2 += __shfl_xor(p2, mm);
            p3 += __shfl_xor(p3, mm);
        }
        // transpose: this lane keeps the logit of its own batch-row `lo`
        int sl = (lo >> 2) * 16;
        float t0 = __shfl(p0, sl), t1 = __shfl(p1, sl);
        float t2 = __shfl(p2, sl), t3 = __shfl(p3, sl);
        int r = lo & 3;
        float w = (r == 0) ? t0 : (r == 1) ? t1 : (r == 2) ? t2 : t3;

        // flash update (masked l: no-op)
        bool valid = (l <= sq);
        float mn = valid ? fmaxf(m, w) : m;
        float c = __expf(m - mn);              // ==1 when max unchanged; ==0 on first l
        float e = valid ? __expf(w - mn) : 0.f;
        s = s * c + e;
        m = mn;
        // o-update from hi+lo (exact fp32 sum of the two bf16 parts)
#pragma unroll
        for (int kt = 0; kt < 4; ++kt) {
            union { short8 v; unsigned u[4]; } uh, ul;
            uh.v = af[kt];
            ul.v = alo[kt];
#pragma unroll
            for (int q = 0; q < 4; ++q) {
                float h0 = __uint_as_float(uh.u[q] << 16);
                float h1 = __uint_as_float(uh.u[q] & 0xffff0000u);
                float l0 = __uint_as_float(ul.u[q] << 16);
                float l1 = __uint_as_float(ul.u[q] & 0xffff0000u);
                o[kt][2 * q]     = o[kt][2 * q] * c + e * (h0 + l0);
                o[kt][2 * q + 1] = o[kt][2 * q + 1] * c + e * (h1 + l1);
            }
        }
    }

    // normalize; split O into bf16 hi+lo fc A-fragments (row = lo, k = kt*32+g*8+j)
    const float rs = 1.f / s;  // s>0 always: l=0 is always valid (sq >= 0)
    short8 afoh[4], afol[4];
#pragma unroll
    for (int kt = 0; kt < 4; ++kt) {
        union { unsigned u[4]; short8 v; } uh, ul;
#pragma unroll
        for (int p = 0; p < 4; ++p) {
            float x = o[kt][2 * p] * rs, y = o[kt][2 * p + 1] * rs;
            unsigned hx = rne16(x), hy = rne16(y);
            uh.u[p] = hx | (hy << 16);
            ul.u[p] = rne_bf16_pair(x - __uint_as_float(hx << 16),
                                    y - __uint_as_float(hy << 16));
        }
        afoh[kt] = uh.v;
        afol[kt] = ul.v;
    }

    __syncthreads();
    // ---------- phase 5: fcw hi/lo fragments -> LDS (hi: [0,1024), lo: [1024,2048)) --
    stage_bfrags_split(fcw, 128, 4, wlds, wlds + 1024, tid);
    __syncthreads();

    // ---------- phase 6: out = relu(O @ fcw^T + fcb), split-bf16 (3 cross terms) ----
    {
        f32x4 facc[4];
#pragma unroll
        for (int ct = 0; ct < 4; ++ct) {
            float fb = fcb[ct * 16 + lo];
            facc[ct] = (f32x4){fb, fb, fb, fb};
        }
#pragma unroll
        for (int kt = 0; kt < 4; ++kt)
#pragma unroll
            for (int ct = 0; ct < 4; ++ct) {
                short8 wh = wlds[(kt * 4 + ct) * 64 + lane];
                short8 wl = wlds[1024 + (kt * 4 + ct) * 64 + lane];
                facc[ct] = __builtin_amdgcn_mfma_f32_16x16x32_bf16(afoh[kt], wh, facc[ct], 0, 0, 0);
                facc[ct] = __builtin_amdgcn_mfma_f32_16x16x32_bf16(afol[kt], wh, facc[ct], 0, 0, 0);
                facc[ct] = __builtin_amdgcn_mfma_f32_16x16x32_bf16(afoh[kt], wl, facc[ct], 0, 0, 0);
            }
#pragma unroll
        for (int ct = 0; ct < 4; ++ct) {
            float v0 = fmaxf(facc[ct].x, 0.f), v1 = fmaxf(facc[ct].y, 0.f);
            float v2 = fmaxf(facc[ct].z, 0.f), v3 = fmaxf(facc[ct].w, 0.f);
            long long bo = b0w + g * 4;
            if (bo + 0 < B) out[(bo + 0) * 64 + ct * 16 + lo] = v0;
            if (bo + 1 < B) out[(bo + 1) * 64 + ct * 16 + lo] = v1;
            if (bo + 2 < B) out[(bo + 2) * 64 + ct * 16 + lo] = v2;
            if (bo + 3 < B) out[(bo + 3) * 64 + ct * 16 + lo] = v3;
        }
    }
}

extern "C" void kernel_launch(void* const* d_in, const int* in_sizes, int n_in,
                              void* d_out, int out_size, void* d_ws, size_t ws_size,
                              hipStream_t stream) {
    const float* value = (const float*)d_in[0];
    const float* key   = (const float*)d_in[1];
    const int*   seq   = (const int*)d_in[2];
    // d_in[3] = maxlen (unused; L == 9 fixed by reference)
    const float* w1    = (const float*)d_in[4];
    const float* b1    = (const float*)d_in[5];
    const float* w2    = (const float*)d_in[6];
    // d_in[7] = b2: softmax-invariant, dropped
    const float* fcw   = (const float*)d_in[8];
    const float* fcb   = (const float*)d_in[9];
    float* out = (float*)d_out;

    int B = in_sizes[1] / 128;
    int blocks = (B + BPB - 1) / BPB;
    mask_attn_fused<<<blocks, NW * 64, 0, stream>>>(value, key, seq, w1, b1, w2, fcw, fcb, out, B);
}

// Round 9
// 89.068 us; speedup vs baseline: 4.8004x; 1.0109x over previous
//
#include <hip/hip_runtime.h>
#include <hip/hip_bf16.h>

typedef __attribute__((ext_vector_type(8))) short short8;   // 8 x bf16 bits = 4 VGPRs
typedef __attribute__((ext_vector_type(4))) float f32x4;

#define NW 8            // waves per block (512 threads)
#define BPW 16          // batches per wave
#define BPB (NW * BPW)  // 128 batches per block

static __device__ __forceinline__ unsigned pk_bf16(float a, float b) {
    unsigned d;
    asm("v_cvt_pk_bf16_f32 %0, %1, %2" : "=v"(d) : "v"(a), "v"(b));
    return d;
}

// round-to-nearest-even bf16, returning the 16 bits
static __device__ __forceinline__ unsigned rne16(float x) {
    unsigned u = __float_as_uint(x);
    return (u + 0x7fffu + ((u >> 16) & 1u)) >> 16;
}
static __device__ __forceinline__ unsigned rne_bf16_pair(float x, float y) {
    return rne16(x) | (rne16(y) << 16);
}

static __device__ __forceinline__ short8 pack_frag(f32x4 a, f32x4 b) {
    union { unsigned u[4]; short8 s; } u;
    u.u[0] = pk_bf16(a.x, a.y);
    u.u[1] = pk_bf16(a.z, a.w);
    u.u[2] = pk_bf16(b.x, b.y);
    u.u[3] = pk_bf16(b.z, b.w);
    return u.s;
}

// Stage fragments of W (W[n][k]) into LDS. Same lane map serves as A-frag
// (m = lane&15 -> row n of W) or B-frag: entry idx = (kt*nct + ct)*64 + lane;
// lane holds 8 bf16 with k = kt*32 + (lane>>4)*8 + j, outer = ct*16 + (lane&15).
static __device__ __forceinline__ void stage_bfrags(const float* __restrict__ w,
                                                    int row_stride, int k_off, int nct,
                                                    short8* lds, int tid) {
    const int total = 4 * nct * 64;
    for (int idx = tid; idx < total; idx += NW * 64) {
        int lane = idx & 63;
        int ct = (idx >> 6) % nct;
        int kt = idx / (64 * nct);
        int n = ct * 16 + (lane & 15);
        int k = kt * 32 + (lane >> 4) * 8;
        const float* p = w + (size_t)n * row_stride + k_off + k;
        f32x4 a = *(const f32x4*)p;
        f32x4 b = *(const f32x4*)(p + 4);
        lds[idx] = pack_frag(a, b);
    }
}

// Same, but split each element into bf16 hi + bf16 residual (hi -> lds_hi, lo -> lds_lo).
static __device__ __forceinline__ void stage_bfrags_split(const float* __restrict__ w,
                                                          int row_stride, int nct,
                                                          short8* lds_hi, short8* lds_lo,
                                                          int tid) {
    const int total = 4 * nct * 64;
    for (int idx = tid; idx < total; idx += NW * 64) {
        int lane = idx & 63;
        int ct = (idx >> 6) % nct;
        int kt = idx / (64 * nct);
        int n = ct * 16 + (lane & 15);
        int k = kt * 32 + (lane >> 4) * 8;
        const float* p = w + (size_t)n * row_stride + k;
        f32x4 a = *(const f32x4*)p;
        f32x4 b = *(const f32x4*)(p + 4);
        float xs[8] = {a.x, a.y, a.z, a.w, b.x, b.y, b.z, b.w};
        union { unsigned u[4]; short8 s; } uh, ul;
#pragma unroll
        for (int q = 0; q < 4; ++q) {
            float x = xs[2 * q], y = xs[2 * q + 1];
            unsigned hx = rne16(x), hy = rne16(y);
            uh.u[q] = hx | (hy << 16);
            ul.u[q] = rne_bf16_pair(x - __uint_as_float(hx << 16),
                                    y - __uint_as_float(hy << 16));
        }
        lds_hi[idx] = uh.s;
        lds_lo[idx] = ul.s;
    }
}

// MEASURED launch-bounds rule on gfx950 hipcc (3 points: (512,4)->64,
// (512,3)->84, (256,3)->84): VGPR cap = 256 / arg, independent of block size.
// (512,2) -> hard 128 cap; live set ~116 fits. LDS 65KB -> 2 blocks/CU ->
// 4 waves/SIMD.
// R9 change: SWAPPED logit GEMM — C[h][b] = W·x^T (weights as A-operand from
// LDS, key/value packs as B-operand). Same staged bytes, same register packs;
// the per-l cross-lane reduce collapses from 5 swizzle levels + 4-shfl
// transpose (~29 serial cross-lane ops) to 2 shfl_xor, and the logit lands
// in every lane of its batch column (no transpose).
__global__ __launch_bounds__(NW * 64, 2)
void mask_attn_fused(const float* __restrict__ value, const float* __restrict__ key,
                     const int* __restrict__ seq_len, const float* __restrict__ w1,
                     const float* __restrict__ b1, const float* __restrict__ w2,
                     const float* __restrict__ fcw, const float* __restrict__ fcb,
                     float* __restrict__ out, int B) {
    __shared__ short8 wlds[2048];            // 32 KiB: Wk -> Wv -> (fcw_hi|fcw_lo)
    __shared__ uint2 hklds[NW * 8 * 64];     // 32 KiB: per-wave hk^T init (bf16-pair bits)
    __shared__ f32x4 w2lds4[32];             // 512 B: w2 as f32x4[ct*4+g]

    const int tid = threadIdx.x;
    const int wave = tid >> 6;
    const int lane = tid & 63;
    const int g = lane >> 4;   // 0..3
    const int lo = lane & 15;  // 0..15

    const long long b0w = (long long)blockIdx.x * BPB + (long long)wave * BPW;
    long long vb = b0w + lo; if (vb > (long long)B - 1) vb = (long long)B - 1;

    // ---------- prologue: issue tile-0 value loads + key loads FIRST ----------
    const float* ap = value + vb * (9 * 128) + g * 8;
    f32x4 raw[8];
#pragma unroll
    for (int h = 0; h < 8; ++h)
        raw[h] = *(const f32x4*)(ap + (h >> 1) * 32 + (h & 1) * 4);
    f32x4 kv[8];
    const float* kp = key + vb * 128 + g * 8;
#pragma unroll
    for (int h = 0; h < 8; ++h)
        kv[h] = *(const f32x4*)(kp + (h >> 1) * 32 + (h & 1) * 4);

    if (tid < 32) w2lds4[tid] = ((const f32x4*)w2)[tid];

    // ---------- phase 1: Wk fragments -> LDS ----------
    stage_bfrags(w1, 2 * 128, 0, 8, wlds, tid);
    __syncthreads();

    // ---------- phase 2 (swapped): C2[h][b] = b1[h] + Wk·key^T ----------
    // C/D layout: row h = ct*16 + g*4 + reg, col b = lane&15.
    {
        short8 kf[4];
#pragma unroll
        for (int kt = 0; kt < 4; ++kt)
            kf[kt] = pack_frag(kv[2 * kt], kv[2 * kt + 1]);
#pragma unroll
        for (int ct = 0; ct < 8; ++ct) {
            f32x4 acc = *(const f32x4*)(b1 + ct * 16 + g * 4);  // rows g*4..g*4+3
#pragma unroll
            for (int kt = 0; kt < 4; ++kt)
                acc = __builtin_amdgcn_mfma_f32_16x16x32_bf16(
                    wlds[(kt * 8 + ct) * 64 + lane], kf[kt], acc, 0, 0, 0);
            uint2 pk;
            pk.x = rne_bf16_pair(acc.x, acc.y);
            pk.y = rne_bf16_pair(acc.z, acc.w);
            hklds[wave * 512 + ct * 64 + lane] = pk;
        }
    }
    __syncthreads();

    // ---------- phase 3: Wv fragments -> LDS ----------
    stage_bfrags(w1, 2 * 128, 128, 8, wlds, tid);
    __syncthreads();

    const int sq = seq_len[vb];  // valid positions: l <= sq (this lane's batch = lo)
    const uint2* hkw = hklds + wave * 512;

    // ---------- phase 4: pipelined fused l-loop (swapped GEMM) ----------
    float o[4][8];
#pragma unroll
    for (int kt = 0; kt < 4; ++kt)
#pragma unroll
        for (int j = 0; j < 8; ++j) o[kt][j] = 0.f;
    float s = 0.f, m = -3e38f;

#pragma unroll 1
    for (int l = 0; l < 9; ++l) {
        // convert: raw -> af (bf16 hi) + alo (bf16 residual); then raw is reusable
        short8 af[4], alo[4];
#pragma unroll
        for (int kt = 0; kt < 4; ++kt) {
            f32x4 a = raw[2 * kt], b = raw[2 * kt + 1];
            af[kt] = pack_frag(a, b);
            float xs[8] = {a.x, a.y, a.z, a.w, b.x, b.y, b.z, b.w};
            union { unsigned u[4]; short8 s; } ul;
#pragma unroll
            for (int q = 0; q < 4; ++q) {
                float x = xs[2 * q], y = xs[2 * q + 1];
                unsigned hx = rne16(x), hy = rne16(y);
                ul.u[q] = pk_bf16(x - __uint_as_float(hx << 16),
                                  y - __uint_as_float(hy << 16));
            }
            alo[kt] = ul.s;
        }
        // issue next tile's loads into raw (in flight under the whole chain below)
        if (l + 1 < 9) {
#pragma unroll
            for (int h = 0; h < 8; ++h)
                raw[h] = *(const f32x4*)(ap + (l + 1) * 128 + (h >> 1) * 32 + (h & 1) * 4);
        }

        // swapped logit GEMM: acc[h-tile][b], weights A from LDS, value B in regs.
        // Two partial chains for ILP; per-lane partial over its 32 h-rows.
        float pA = 0.f, pB = 0.f;
#pragma unroll
        for (int ct = 0; ct < 8; ++ct) {
            uint2 hkv = hkw[ct * 64 + lane];
            f32x4 acc;
            acc.x = __uint_as_float(hkv.x << 16);
            acc.y = __uint_as_float(hkv.x & 0xffff0000u);
            acc.z = __uint_as_float(hkv.y << 16);
            acc.w = __uint_as_float(hkv.y & 0xffff0000u);
#pragma unroll
            for (int kt = 0; kt < 4; ++kt)
                acc = __builtin_amdgcn_mfma_f32_16x16x32_bf16(
                    wlds[(kt * 8 + ct) * 64 + lane], af[kt], acc, 0, 0, 0);
            f32x4 wv = w2lds4[ct * 4 + g];  // w2[ct*16+g*4 .. +3], broadcast read
            if (ct & 1) {
                pB += fmaxf(acc.x, 0.f) * wv.x;
                pB += fmaxf(acc.y, 0.f) * wv.y;
                pB += fmaxf(acc.z, 0.f) * wv.z;
                pB += fmaxf(acc.w, 0.f) * wv.w;
            } else {
                pA += fmaxf(acc.x, 0.f) * wv.x;
                pA += fmaxf(acc.y, 0.f) * wv.y;
                pA += fmaxf(acc.z, 0.f) * wv.z;
                pA += fmaxf(acc.w, 0.f) * wv.w;
            }
        }
        float p = pA + pB;
        p += __shfl_xor(p, 16);
        p += __shfl_xor(p, 32);
        float w = p;  // logit of batch lo, present in every lane of the column

        // flash update (masked l: no-op)
        bool valid = (l <= sq);
        float mn = valid ? fmaxf(m, w) : m;
        float c = __expf(m - mn);              // ==1 when max unchanged; ==0 on first l
        float e = valid ? __expf(w - mn) : 0.f;
        s = s * c + e;
        m = mn;
        // o-update from hi+lo (exact fp32 sum of the two bf16 parts)
#pragma unroll
        for (int kt = 0; kt < 4; ++kt) {
            union { short8 v; unsigned u[4]; } uh, ul;
            uh.v = af[kt];
            ul.v = alo[kt];
#pragma unroll
            for (int q = 0; q < 4; ++q) {
                float h0 = __uint_as_float(uh.u[q] << 16);
                float h1 = __uint_as_float(uh.u[q] & 0xffff0000u);
                float l0 = __uint_as_float(ul.u[q] << 16);
                float l1 = __uint_as_float(ul.u[q] & 0xffff0000u);
                o[kt][2 * q]     = o[kt][2 * q] * c + e * (h0 + l0);
                o[kt][2 * q + 1] = o[kt][2 * q + 1] * c + e * (h1 + l1);
            }
        }
    }

    // normalize; split O into bf16 hi+lo fc A-fragments (row = lo, k = kt*32+g*8+j)
    const float rs = 1.f / s;  // s>0 always: l=0 is always valid (sq >= 0)
    short8 afoh[4], afol[4];
#pragma unroll
    for (int kt = 0; kt < 4; ++kt) {
        union { unsigned u[4]; short8 v; } uh, ul;
#pragma unroll
        for (int p = 0; p < 4; ++p) {
            float x = o[kt][2 * p] * rs, y = o[kt][2 * p + 1] * rs;
            unsigned hx = rne16(x), hy = rne16(y);
            uh.u[p] = hx | (hy << 16);
            ul.u[p] = rne_bf16_pair(x - __uint_as_float(hx << 16),
                                    y - __uint_as_float(hy << 16));
        }
        afoh[kt] = uh.v;
        afol[kt] = ul.v;
    }

    __syncthreads();
    // ---------- phase 5: fcw hi/lo fragments -> LDS (hi: [0,1024), lo: [1024,2048)) --
    stage_bfrags_split(fcw, 128, 4, wlds, wlds + 1024, tid);
    __syncthreads();

    // ---------- phase 6: out = relu(O @ fcw^T + fcb), split-bf16 (3 cross terms) ----
    {
        f32x4 facc[4];
#pragma unroll
        for (int ct = 0; ct < 4; ++ct) {
            float fb = fcb[ct * 16 + lo];
            facc[ct] = (f32x4){fb, fb, fb, fb};
        }
#pragma unroll
        for (int kt = 0; kt < 4; ++kt)
#pragma unroll
            for (int ct = 0; ct < 4; ++ct) {
                short8 wh = wlds[(kt * 4 + ct) * 64 + lane];
                short8 wl = wlds[1024 + (kt * 4 + ct) * 64 + lane];
                facc[ct] = __builtin_amdgcn_mfma_f32_16x16x32_bf16(afoh[kt], wh, facc[ct], 0, 0, 0);
                facc[ct] = __builtin_amdgcn_mfma_f32_16x16x32_bf16(afol[kt], wh, facc[ct], 0, 0, 0);
                facc[ct] = __builtin_amdgcn_mfma_f32_16x16x32_bf16(afoh[kt], wl, facc[ct], 0, 0, 0);
            }
#pragma unroll
        for (int ct = 0; ct < 4; ++ct) {
            float v0 = fmaxf(facc[ct].x, 0.f), v1 = fmaxf(facc[ct].y, 0.f);
            float v2 = fmaxf(facc[ct].z, 0.f), v3 = fmaxf(facc[ct].w, 0.f);
            long long bo = b0w + g * 4;
            if (bo + 0 < B) out[(bo + 0) * 64 + ct * 16 + lo] = v0;
            if (bo + 1 < B) out[(bo + 1) * 64 + ct * 16 + lo] = v1;
            if (bo + 2 < B) out[(bo + 2) * 64 + ct * 16 + lo] = v2;
            if (bo + 3 < B) out[(bo + 3) * 64 + ct * 16 + lo] = v3;
        }
    }
}

extern "C" void kernel_launch(void* const* d_in, const int* in_sizes, int n_in,
                              void* d_out, int out_size, void* d_ws, size_t ws_size,
                              hipStream_t stream) {
    const float* value = (const float*)d_in[0];
    const float* key   = (const float*)d_in[1];
    const int*   seq   = (const int*)d_in[2];
    // d_in[3] = maxlen (unused; L == 9 fixed by reference)
    const float* w1    = (const float*)d_in[4];
    const float* b1    = (const float*)d_in[5];
    const float* w2    = (const float*)d_in[6];
    // d_in[7] = b2: softmax-invariant, dropped
    const float* fcw   = (const float*)d_in[8];
    const float* fcb   = (const float*)d_in[9];
    float* out = (float*)d_out;

    int B = in_sizes[1] / 128;
    int blocks = (B + BPB - 1) / BPB;
    mask_attn_fused<<<blocks, NW * 64, 0, stream>>>(value, key, seq, w1, b1, w2, fcw, fcb, out, B);
}